// Round 8
// baseline (5049.656 us; speedup 1.0000x reference)
//
#include <hip/hip_runtime.h>
#include <stdint.h>

// Problem constants (fixed by reference)
#define TT 256
#define FF 128
#define HH 256
#define BB 256
#define BTc (BB * TT)                    // 65536
#define BTFc ((size_t)BB * TT * FF)      // 8388608 elements per output tensor

typedef __attribute__((ext_vector_type(8))) short short8;
typedef __attribute__((ext_vector_type(4))) float floatx4;
typedef __attribute__((ext_vector_type(4))) int intx4;

__device__ __forceinline__ floatx4 mfma16(short8 a, short8 b, floatx4 c) {
    return __builtin_amdgcn_mfma_f32_16x16x32_bf16(a, b, c, 0, 0, 0);
}
__device__ __forceinline__ intx4 mfmai8(long a, long b, intx4 c) {
    return __builtin_amdgcn_mfma_i32_16x16x32_i8(a, b, c, 0, 0, 0);
}

__device__ __forceinline__ float bf2f(short s) {
    return __uint_as_float(((unsigned)(unsigned short)s) << 16);
}
__device__ __forceinline__ short f2bf(float f) {  // RNE
    unsigned u = __float_as_uint(f);
    u += 0x7FFFu + ((u >> 16) & 1u);
    return (short)(u >> 16);
}
__device__ __forceinline__ short8 ld_cvt8(const float* __restrict__ p) {
    short8 r;
#pragma unroll
    for (int j = 0; j < 8; ++j) r[j] = f2bf(p[j]);
    return r;
}
__device__ __forceinline__ float sigf(float x) { return 1.f / (1.f + __expf(-x)); }
__device__ __forceinline__ float tanhf_(float x) { return 1.f - 2.f / (1.f + __expf(2.f * x)); }

// lgkm-only barrier: LDS handoffs need lgkmcnt(0); global loads/stores get
// their vmcnt waits at USE (compiler-inserted).
#define BARSYNC() do { asm volatile("s_waitcnt lgkmcnt(0)" ::: "memory"); \
                       __builtin_amdgcn_s_barrier(); } while (0)

// ---------------------------------------------------------------------------
// Phase-A launch 1: k_a = prep (fp32->bf16 casts) UNION scales (row absmax)
// UNION packb (bf16 frag packs). All mutually independent.
// ---------------------------------------------------------------------------
struct PrepArgs {
    const float *s0, *s1, *s2, *s3, *s4, *s5, *s6;
    short *d0, *d1, *d2, *d3, *d4, *d5, *d6;
};
struct ScaleDesc { const float* src; int stride; int coloff; int K; int nrows; int sbase; };
struct ScaleArgs { ScaleDesc d[6]; float* s; };
struct PackBDesc { const float* src; short* dst; int stride; int coloff; int kts; int diag; int groups; };
struct AArgs { PrepArgs p; ScaleArgs s; PackBDesc b[6]; };

__global__ __launch_bounds__(256) void k_a(AArgs A) {
    if (blockIdx.x < 1472) {
        int i = blockIdx.x * 256 + threadIdx.x;
        const PrepArgs& P = A.p;
        if (i < 32768) { P.d0[i] = f2bf(P.s0[i]); return; }  i -= 32768;
        if (i < 32768) { P.d1[i] = f2bf(P.s1[i]); return; }  i -= 32768;
        if (i < 32768) { P.d2[i] = f2bf(P.s2[i]); return; }  i -= 32768;
        if (i < 32768) { P.d3[i] = f2bf(P.s3[i]); return; }  i -= 32768;
        if (i < 98304) { P.d4[i] = f2bf(P.s4[i]); return; }  i -= 98304;
        if (i < 98304) { P.d5[i] = f2bf(P.s5[i]); return; }  i -= 98304;
        if (i < 49152) { P.d6[i] = f2bf(P.s6[i]); return; }
        return;
    }
    if (blockIdx.x < 2560) {
        int gw = ((blockIdx.x - 1472) * 256 + threadIdx.x) >> 6;
        int lane = threadIdx.x & 63;
#pragma unroll 1
        for (int i = 0; i < 6; ++i) {
            if (gw < A.s.d[i].nrows) {
                const float* p = A.s.d[i].src + (size_t)gw * A.s.d[i].stride + A.s.d[i].coloff;
                float amax = 0.f;
                for (int j = lane; j < A.s.d[i].K; j += 64) amax = fmaxf(amax, fabsf(p[j]));
#pragma unroll
                for (int off = 32; off; off >>= 1) amax = fmaxf(amax, __shfl_xor(amax, off, 64));
                if (lane == 0) A.s.s[A.s.d[i].sbase + gw] = fmaxf(amax, 1e-20f);
                return;
            }
            gw -= A.s.d[i].nrows;
        }
        return;
    }
    int g = (blockIdx.x - 2560) * 256 + threadIdx.x;
#pragma unroll 1
    for (int i = 0; i < 6; ++i) {
        const PackBDesc& D = A.b[i];
        if (g < D.groups) {
            int frag = g >> 6, lane = g & 63;
            int nt = frag >> 2, kt = frag & 3;   // kts==4 for all entries
            int ln = lane & 15, q4 = lane >> 4;
            int row = nt * 16 + ln;
            const float* p = D.src + (size_t)row * D.stride + D.coloff + kt * 32 + q4 * 8;
            short* dp = D.dst + (size_t)g * 8;
#pragma unroll
            for (int j = 0; j < 8; ++j) {
                int col = kt * 32 + q4 * 8 + j;
                float v = p[j];
                if (D.diag && col == row) v = 0.f;
                dp[j] = f2bf(v);
            }
            return;
        }
        g -= D.groups;
    }
}

// ---------------------------------------------------------------------------
// Phase-A launch 2: k_b = rr_rb (blocks 0..1023, longest pole first) UNION
// gbase (1024..3071) UNION packq (3072..3359). All independent.
// ---------------------------------------------------------------------------
struct PackQDesc { const float* src; char* dst; int stride; int coloff; int kts; int sbase; int groups; };
struct BArgs {
    // rr_rb
    const float* lt;
    const short* lagW0; const float* lagb0; const short* rbW0; const float* rbb0;
    short* rr0; short* rb0;
    const short* lagW1; const float* lagb1; const short* rbW1; const float* rbb1;
    short* rr1; short* rb1;
    // gbase
    const float* m;
    const short* wmB0; const short* wmB1;
    short* gb0; short* gb1;
    // packq
    PackQDesc q[4]; const float* s;
};

__global__ __launch_bounds__(256) void k_b(BArgs A) {
    __shared__ short rrS[128][264];          // rr_rb branch only
    const int tid = threadIdx.x, lane = tid & 63, w = tid >> 6;
    const int ln = lane & 15, q4 = lane >> 4;

    if (blockIdx.x < 1024) {
        // ---- rr_rb: rr = exp(-relu(lt @ lagW^T + lagb)) (frag layout),
        //             rb = rr @ rbW^T + rbb ----
        int b = blockIdx.x;
        const int dir = b >> 9; b &= 511;
        const int tc  = b & 7;          // 32-timestep chunk
        const int q4d = (b >> 3) & 3;   // rd group
        const int bg  = b >> 5;         // batch group 0..15
        const short* lagW = dir ? A.lagW1 : A.lagW0;
        const float* lagb = dir ? A.lagb1 : A.lagb0;
        const short* rbW  = dir ? A.rbW1  : A.rbW0;
        const float* rbb  = dir ? A.rbb1  : A.rbb0;
        short* rr = dir ? A.rr1 : A.rr0;
        short* rb = dir ? A.rb1 : A.rb0;
        // tile row r (0..127): batch = bg*16 + q4d*4 + (r>>5), t = tc*32 + (r&31)

#pragma unroll
        for (int mt = 0; mt < 2; ++mt) {
            const int rbase = w * 32 + mt * 16;
            floatx4 acc[16];
#pragma unroll
            for (int nt = 0; nt < 16; ++nt) { floatx4 z = {0.f, 0.f, 0.f, 0.f}; acc[nt] = z; }
            const int r = rbase + ln;
            const size_t aoff = ((size_t)(bg * 16 + q4d * 4 + (r >> 5)) * TT + tc * 32 + (r & 31)) * FF;
#pragma unroll
            for (int kt = 0; kt < 4; ++kt) {
                short8 a = ld_cvt8(A.lt + aoff + kt * 32 + q4 * 8);
#pragma unroll
                for (int nt = 0; nt < 16; ++nt) {
                    short8 bfr = *(const short8*)(lagW + (nt * 16 + ln) * 128 + kt * 32 + q4 * 8);
                    acc[nt] = mfma16(a, bfr, acc[nt]);
                }
            }
#pragma unroll
            for (int nt = 0; nt < 16; ++nt) {
                int n = nt * 16 + ln;
                float bias = lagb[n];
#pragma unroll
                for (int r2 = 0; r2 < 4; ++r2) {
                    int row = rbase + q4 * 4 + r2;
                    rrS[row][n] = f2bf(__expf(-fmaxf(acc[nt][r2] + bias, 0.f)));
                }
            }
        }
        __syncthreads();
        // rr store: pack 4 rd-slots into one b64; coalesced.
        for (int c = tid; c < 32 * 256; c += 256) {
            int tl = c >> 8, n = c & 255;
            unsigned long long pk =
                ((unsigned long long)(unsigned short)rrS[tl][n]) |
                ((unsigned long long)(unsigned short)rrS[32 + tl][n] << 16) |
                ((unsigned long long)(unsigned short)rrS[64 + tl][n] << 32) |
                ((unsigned long long)(unsigned short)rrS[96 + tl][n] << 48);
            size_t doff = ((((size_t)(bg * TT + tc * 32 + tl) * 16 + (n >> 4)) * 64)
                           + q4d * 16 + (n & 15)) * 4;
            *(unsigned long long*)(rr + doff) = pk;
        }
#pragma unroll
        for (int mt = 0; mt < 2; ++mt) {
            const int rbase = w * 32 + mt * 16;
            floatx4 acc[8];
#pragma unroll
            for (int nt = 0; nt < 8; ++nt) { floatx4 z = {0.f, 0.f, 0.f, 0.f}; acc[nt] = z; }
#pragma unroll
            for (int kt = 0; kt < 8; ++kt) {
                short8 a = *(const short8*)&rrS[rbase + ln][kt * 32 + q4 * 8];
#pragma unroll
                for (int nt = 0; nt < 8; ++nt) {
                    short8 bfr = *(const short8*)(rbW + (nt * 16 + ln) * 256 + kt * 32 + q4 * 8);
                    acc[nt] = mfma16(a, bfr, acc[nt]);
                }
            }
#pragma unroll
            for (int nt = 0; nt < 8; ++nt) {
                int n = nt * 16 + ln;
                float bias = rbb[n];
#pragma unroll
                for (int r2 = 0; r2 < 4; ++r2) {
                    int row = rbase + q4 * 4 + r2;
                    size_t roff = ((size_t)(bg * 16 + q4d * 4 + (row >> 5)) * TT
                                   + tc * 32 + (row & 31)) * 128;
                    rb[roff + n] = f2bf(acc[nt][r2] + bias);
                }
            }
        }
        return;
    }

    if (blockIdx.x < 3072) {
        // ---- gbase: gbase[b,t,n] = WihM @ m(b,t)  (bf16, scan frag layout) ----
        int task = (blockIdx.x - 1024) * 4 + w;   // 0..8191
        const int dir = task >> 12; task &= 4095; // bg*256 + t
        const int bg = task >> 8, t = task & 255;
        const short* wB = dir ? A.wmB1 : A.wmB0;
        short* gb = dir ? A.gb1 : A.gb0;

        short8 a[4];
#pragma unroll
        for (int kt = 0; kt < 4; ++kt)
            a[kt] = ld_cvt8(A.m + ((size_t)(bg * 16 + ln) * TT + t) * FF + kt * 32 + q4 * 8);

        short* dst = gb + (size_t)task * 16384 + lane * 4;
#pragma unroll 2
        for (int nt = 0; nt < 64; ++nt) {
            floatx4 acc = {0.f, 0.f, 0.f, 0.f};
#pragma unroll
            for (int kt = 0; kt < 4; ++kt) {
                short8 bfr = *(const short8*)(wB + (nt * 4 + kt) * 512 + lane * 8);
                acc = mfma16(a[kt], bfr, acc);
            }
            unsigned long long pk =
                ((unsigned long long)(unsigned short)f2bf(acc[0])) |
                ((unsigned long long)(unsigned short)f2bf(acc[1]) << 16) |
                ((unsigned long long)(unsigned short)f2bf(acc[2]) << 32) |
                ((unsigned long long)(unsigned short)f2bf(acc[3]) << 48);
            *(unsigned long long*)(dst + nt * 256) = pk;
        }
        return;
    }

    // ---- packq ----
    int g = (blockIdx.x - 3072) * 256 + tid;
#pragma unroll 1
    for (int i = 0; i < 4; ++i) {
        const PackQDesc& D = A.q[i];
        if (g < D.groups) {
            int frag = g >> 6, plane = g & 63;
            int nt = frag / D.kts, kt = frag - nt * D.kts;
            int pln = plane & 15, pq4 = plane >> 4;
            int row = nt * 16 + pln;
            const float* p = D.src + (size_t)row * D.stride + D.coloff + kt * 32 + pq4 * 8;
            float inv = 127.f / A.s[D.sbase + row];
            char* dp = D.dst + (size_t)g * 8;
#pragma unroll
            for (int j = 0; j < 8; ++j) {
                int q = __float2int_rn(p[j] * inv);
                q = q > 127 ? 127 : (q < -127 ? -127 : q);
                dp[j] = (char)q;
            }
            return;
        }
        g -= D.groups;
    }
}

// ---------------------------------------------------------------------------
// Phase-A launch 3: k_beta2 — both dirs, 32-row blocks (uS = 25 KB -> ~5
// blocks/CU; was 50 KB -> 3). Wave w: row-tile rt=w>>1, n-half nh=w&1.
//   u = sigmoid(concat(m, rb) @ bW^T + bb); beta = u @ tW^T + tb
// ---------------------------------------------------------------------------
__global__ __launch_bounds__(256) void k_beta2(
    const float* __restrict__ m,
    const short* __restrict__ rb0, const short* __restrict__ rb1,
    const short* __restrict__ bW0, const short* __restrict__ bW1,
    const float* __restrict__ bb0, const float* __restrict__ bb1,
    const short* __restrict__ tW, const float* __restrict__ tb,
    short* __restrict__ bout0, short* __restrict__ bout1) {
    __shared__ short uS[32][392];
    const int tid = threadIdx.x, lane = tid & 63, w = tid >> 6;
    const int ln = lane & 15, q4 = lane >> 4;
    const int dir = blockIdx.x >> 11;                 // 2048 blocks per dir
    const size_t r0 = (size_t)(blockIdx.x & 2047) * 32;
    const short* rb = dir ? rb1 : rb0;
    const short* bW = dir ? bW1 : bW0;
    const float* bb = dir ? bb1 : bb0;
    short* bout = dir ? bout1 : bout0;
    const int rt = w >> 1;        // row-tile 0/1 (rows rt*16 .. +16)
    const int nh = w & 1;         // n-half

    {
        floatx4 acc[12];
#pragma unroll
        for (int j = 0; j < 12; ++j) { floatx4 z = {0.f, 0.f, 0.f, 0.f}; acc[j] = z; }
#pragma unroll
        for (int kt = 0; kt < 8; ++kt) {
            short8 a;
            if (kt < 4) a = ld_cvt8(m + (r0 + rt * 16 + ln) * 128 + kt * 32 + q4 * 8);
            else        a = *(const short8*)(rb + (r0 + rt * 16 + ln) * 128 + (kt - 4) * 32 + q4 * 8);
#pragma unroll
            for (int j = 0; j < 12; ++j) {
                int nt = nh * 12 + j;
                short8 b = *(const short8*)(bW + (nt * 16 + ln) * 256 + kt * 32 + q4 * 8);
                acc[j] = mfma16(a, b, acc[j]);
            }
        }
#pragma unroll
        for (int j = 0; j < 12; ++j) {
            int n = (nh * 12 + j) * 16 + ln;
            float bias = bb[n];
#pragma unroll
            for (int r = 0; r < 4; ++r)
                uS[rt * 16 + q4 * 4 + r][n] = f2bf(sigf(acc[j][r] + bias));
        }
    }
    __syncthreads();
    {
        floatx4 acc[4];
#pragma unroll
        for (int j = 0; j < 4; ++j) { floatx4 z = {0.f, 0.f, 0.f, 0.f}; acc[j] = z; }
#pragma unroll
        for (int kt = 0; kt < 12; ++kt) {
            short8 a = *(const short8*)&uS[rt * 16 + ln][kt * 32 + q4 * 8];
#pragma unroll
            for (int j = 0; j < 4; ++j) {
                int nt = nh * 4 + j;
                short8 b = *(const short8*)(tW + (nt * 16 + ln) * 384 + kt * 32 + q4 * 8);
                acc[j] = mfma16(a, b, acc[j]);
            }
        }
#pragma unroll
        for (int j = 0; j < 4; ++j) {
            int n = (nh * 4 + j) * 16 + ln;
            float bias = tb[n];
#pragma unroll
            for (int r = 0; r < 4; ++r)
                bout[(r0 + rt * 16 + q4 * 4 + r) * 128 + n] = f2bf(acc[j][r] + bias);
        }
    }
}

// ---------------------------------------------------------------------------
// k_scan v6 = v4 schedule (3-barrier role-split, FROZEN structure) with the
// per-step 64-bit address chains replaced by incremental pointers (the tn
// clamp becomes "skip the advance on the last iterations" — wave-uniform),
// and lin's depth-8 MFMA chain split into two depth-4 chains (bit-identical:
// i32 adds are associative).
// ---------------------------------------------------------------------------
struct ScanArgs {
    const float* x; const float* m;
    const short* rr0; const short* rr1;      // frag layout (see k_b)
    const short* beta0; const short* beta1;
    const short* gb0; const short* gb1;      // gbase frag layout
    const char* whh0; const char* whh1;
    const char* lin0; const char* lin1;
    const short* wihc0; const short* wihc1;
    const short* zw0; const short* zw1;
    const float* s_all;
    const float* bih0; const float* bhh0; const float* bih1; const float* bhh1;
    const float* linb0; const float* linb1; const float* zb0; const float* zb1;
    float* out;
};

__global__ __launch_bounds__(1024, 4) void k_scan(ScanArgs A) {
    const int tid = threadIdx.x;
    const int lane = tid & 63;
    const int w = tid >> 6;       // 0..15
    const int ln = lane & 15;
    const int q4 = lane >> 4;     // 0..3
    const int dir = blockIdx.x >> 4;
    const int bgi = blockIdx.x & 15;
    const int bg0 = bgi * 16;

    const short* rrF   = dir ? A.rr1   : A.rr0;
    const short* beta  = dir ? A.beta1 : A.beta0;
    const short* gbF   = dir ? A.gb1   : A.gb0;
    const char*  whhQ  = dir ? A.whh1  : A.whh0;
    const char*  linQ  = dir ? A.lin1  : A.lin0;
    const short* wihcB = dir ? A.wihc1 : A.wihc0;
    const short* zwB   = dir ? A.zw1   : A.zw0;
    const float* bih   = dir ? A.bih1  : A.bih0;
    const float* bhh   = dir ? A.bhh1  : A.bhh0;
    const float* linb  = dir ? A.linb1 : A.linb0;
    const float* zb    = dir ? A.zb1   : A.zb0;
    const int so_whh  = dir ? 1024 : 0;
    const int so_lin  = 4096 + (dir ? 128 : 0);

    __shared__ char  hS8[16][264];    // h  in i8 (x127)
    __shared__ char  hrS8[16][264];   // h*r in i8 (x127)
    __shared__ char  msS8[16][136];   // m in i8 {0,1}
    __shared__ short xS[16][136];     // x(t) rows, bf16
    __shared__ short bS[16][136];     // beta(t) rows, bf16
    __shared__ short outS[16][136];   // out bf16
    __shared__ short ccS[16][136];    // c_c bf16
    __shared__ short zwS[16384];      // masked zW, bf16 frag-major (32 KB)
    __shared__ char  linS8[32768];    // lin i8 frag-major (32 KB)

    // ---- pinned Whh i8 fragments: 4 gates x 8 kt x 2 VGPR = 64 regs ----
    long WhhP[4][8];
#pragma unroll
    for (int q = 0; q < 4; ++q)
#pragma unroll
        for (int kt = 0; kt < 8; ++kt)
            WhhP[q][kt] = *(const long*)(whhQ + (((w + 16 * q) * 8 + kt) * 512 + lane * 8));

    float fhh[4], gb[4];
#pragma unroll
    for (int q = 0; q < 4; ++q) {
        int n = (w + 16 * q) * 16 + ln;
        fhh[q] = A.s_all[so_whh + n] * (1.f / 16129.f);   // (s/127)*(1/127)
        gb[q]  = bih[n] + bhh[n];
    }
    float flin = 0.f, lb;
    if (w < 8) { int n = w * 16 + ln; flin = A.s_all[so_lin + n] * (1.f / 16129.f); lb = linb[n]; }
    else       { lb = zb[(w - 8) * 16 + ln]; }

    for (int i = tid; i < 16384; i += 1024) zwS[i] = zwB[i];
    for (int i = tid; i < 4096; i += 1024) ((long*)linS8)[i] = ((const long*)linQ)[i];
    for (int i = tid; i < 16 * 264; i += 1024) { hS8[i / 264][i % 264] = 0; hrS8[i / 264][i % 264] = 0; }

    // gates = Whh*(h*r) [i8 pinned] + gbase [prefetched] + bias
    auto GATES = [&](floatx4 (&g)[4], const long (&gq)[4]) {
#pragma unroll
        for (int pass = 0; pass < 2; ++pass) {
            const int q0 = pass * 2, q1 = pass * 2 + 1;
            intx4 gi0 = {0, 0, 0, 0}, gi1 = {0, 0, 0, 0};
#pragma unroll
            for (int kt = 0; kt < 8; ++kt) {
                long hrf = *(const long*)&hrS8[ln][kt * 32 + q4 * 8];
                gi0 = mfmai8(hrf, WhhP[q0][kt], gi0);
                gi1 = mfmai8(hrf, WhhP[q1][kt], gi1);
            }
#pragma unroll
            for (int r = 0; r < 4; ++r) {
                g[q0][r] = (float)gi0[r] * fhh[q0]
                         + bf2f((short)(((unsigned long long)gq[q0]) >> (16 * r))) + gb[q0];
                g[q1][r] = (float)gi1[r] * fhh[q1]
                         + bf2f((short)(((unsigned long long)gq[q1]) >> (16 * r))) + gb[q1];
            }
        }
    };

    const int tfirst = dir ? (TT - 1) : 0;
    const int tsec   = dir ? (TT - 2) : 1;   // tn at tt=0 (TT >= 2)
    {   // stage step-0 row inputs
        float2 xf = *(const float2*)(A.x + ((size_t)(bg0 + w) * TT + tfirst) * FF + lane * 2);
        float2 mf2 = *(const float2*)(A.m + ((size_t)(bg0 + w) * TT + tfirst) * FF + lane * 2);
        int    bf = *(const int*)(beta + ((size_t)(bg0 + w) * TT + tfirst) * FF + lane * 2);
        xS[w][lane * 2 + 0] = f2bf(xf.x);
        xS[w][lane * 2 + 1] = f2bf(xf.y);
        *(int*)&bS[w][lane * 2] = bf;
        msS8[w][lane * 2 + 0] = (char)(mf2.x != 0.f);
        msS8[w][lane * 2 + 1] = (char)(mf2.y != 0.f);
    }
    long gq[4];
#pragma unroll
    for (int q = 0; q < 4; ++q)
        gq[q] = *(const long*)(gbF + (((size_t)(bgi * TT + tfirst) * 64) + (w + 16 * q)) * 256
                                     + lane * 4);

    // ---- per-thread incremental pointers (replace per-step addr chains) ----
    const int sgn = dir ? -1 : 1;
    const float* pXn = A.x  + ((size_t)(bg0 + w) * TT + tsec) * FF + lane * 2;
    const float* pMn = A.m  + ((size_t)(bg0 + w) * TT + tsec) * FF + lane * 2;
    const short* pBn = beta + ((size_t)(bg0 + w) * TT + tsec) * FF + lane * 2;
    const short* pRRn = rrF + ((((size_t)(bgi * TT + tsec) * 16 + w) * 64) + lane) * 4;
    const short* pGQn = gbF + ((size_t)(bgi * TT + tsec) * 64 + w) * 256 + lane * 4;
    // out-store pointers walk t (exactly linear, no clamp)
    float* pO   = A.out + (size_t)dir * 3 * BTFc
                + ((size_t)(bg0 + 2 * w + (lane >> 5)) * TT + tfirst) * FF + (lane & 31) * 4;
    float* pZCV = A.out + (size_t)dir * 3 * BTFc
                + ((size_t)(bg0 + q4 * 4) * TT + tfirst) * FF + (w - 8) * 16 + ln;
    const int dF  = sgn * FF;          // x/m/beta/out element step per t
    const int dRR = sgn * 4096;        // rr shorts per t
    const int dGQ = sgn * 16384;       // gbase shorts per t

    floatx4 cfr = {0.f, 0.f, 0.f, 0.f};
    __syncthreads();

    for (int tt = 0; tt < TT; ++tt) {
        // ---- P0: next-step row prefetches (consumed at P3/next step) ----
        float2 x_nxt = *(const float2*)pXn;
        float2 m_nxt = *(const float2*)pMn;
        int    b_nxt = *(const int*)pBn;
        unsigned long long rrv = *(const unsigned long long*)pRRn;

        // ---- P1: role-split. w>=8: gates.  w<8: out = h @ linW^T + b ----
        floatx4 g[4];
        if (w >= 8) {
            GATES(g, gq);
        } else {
            intx4 oi0 = {0, 0, 0, 0}, oi1 = {0, 0, 0, 0};
#pragma unroll
            for (int kt = 0; kt < 4; ++kt) {
                long lf0 = *(const long*)&linS8[(w * 8 + kt) * 512 + lane * 8];
                long hf0 = *(const long*)&hS8[ln][kt * 32 + q4 * 8];
                oi0 = mfmai8(hf0, lf0, oi0);
                long lf1 = *(const long*)&linS8[(w * 8 + 4 + kt) * 512 + lane * 8];
                long hf1 = *(const long*)&hS8[ln][(4 + kt) * 32 + q4 * 8];
                oi1 = mfmai8(hf1, lf1, oi1);
            }
#pragma unroll
            for (int r = 0; r < 4; ++r)
                outS[q4 * 4 + r][w * 16 + ln] = f2bf((float)(oi0[r] + oi1[r]) * flin + lb);
        }
        BARSYNC();  // A: outS ready

        // ---- P2: w>=8: z-chain.  w<8: own gates + out store ----
        if (w >= 8) {
            floatx4 zv = {lb, lb, lb, lb};
#pragma unroll
            for (int kt = 0; kt < 4; ++kt) {
                const int c8 = kt * 32 + q4 * 8;
                short8 xv = *(const short8*)&xS[ln][c8];
                short8 ov = *(const short8*)&outS[ln][c8];
                unsigned long long mv = *(const unsigned long long*)&msS8[ln][c8];
                short8 xc;
#pragma unroll
                for (int j = 0; j < 8; ++j)
                    xc[j] = ((mv >> (8 * j)) & 0xffULL) ? xv[j] : ov[j];
                short8 zf = *(const short8*)&zwS[((w - 8) * 4 + kt) * 512 + lane * 8];
                zv = mfma16(xc, zf, zv);
            }
#pragma unroll
            for (int r = 0; r < 4; ++r) {
                const int row = q4 * 4 + r, col = (w - 8) * 16 + ln;
                short z16 = f2bf(zv[r]);
                float z0 = bf2f(z16);
                float o  = bf2f(outS[row][col]);
                float b  = bf2f(bS[row][col]);
                float cv = b * z0 + (1.f - b) * o;
                ccS[row][col] = msS8[row][col] ? xS[row][col] : f2bf(cv);
                float* pr = pZCV + (size_t)r * (TT * FF);
                pr[BTFc]     = z0;
                pr[2 * BTFc] = cv;
            }
        } else {
            {   // out store: wave w covers rows 2w, 2w+1
                const int orow = 2 * w + (lane >> 5);
                const int ocol = (lane & 31) * 4;
                long ov4 = *(const long*)&outS[orow][ocol];
                float4 vo;
                vo.x = bf2f((short)(ov4));
                vo.y = bf2f((short)(ov4 >> 16));
                vo.z = bf2f((short)(ov4 >> 32));
                vo.w = bf2f((short)(ov4 >> 48));
                *(float4*)pO = vo;
            }
            GATES(g, gq);
        }
        BARSYNC();  // D: ccS ready

        // ---- P3: gq prefetch (t+1); gates += WihC * c_c; pointwise; stage ----
#pragma unroll
        for (int q = 0; q < 4; ++q)
            gq[q] = *(const long*)(pGQn + q * 4096);
#pragma unroll
        for (int kt = 0; kt < 4; ++kt) {
            short8 ccf = *(const short8*)&ccS[ln][kt * 32 + q4 * 8];
#pragma unroll
            for (int q = 0; q < 4; ++q) {
                short8 wc = *(const short8*)(wihcB + ((w + 16 * q) * 4 + kt) * 512 + lane * 8);
                g[q] = mfma16(ccf, wc, g[q]);
            }
        }
#pragma unroll
        for (int r = 0; r < 4; ++r) {
            float gi_ = g[0][r], gf_ = g[1][r], gg_ = g[2][r], go_ = g[3][r];
            float c2 = sigf(gf_) * cfr[r] + sigf(gi_) * tanhf_(gg_);
            float h2 = sigf(go_) * tanhf_(c2);
            cfr[r] = c2;
            float rv = bf2f((short)(rrv >> (16 * r)));
            hS8[q4 * 4 + r][w * 16 + ln]  = (char)__float2int_rn(h2 * 127.f);
            hrS8[q4 * 4 + r][w * 16 + ln] = (char)__float2int_rn(h2 * rv * 127.f);
        }
        xS[w][lane * 2 + 0] = f2bf(x_nxt.x);
        xS[w][lane * 2 + 1] = f2bf(x_nxt.y);
        *(int*)&bS[w][lane * 2] = b_nxt;
        msS8[w][lane * 2 + 0] = (char)(m_nxt.x != 0.f);
        msS8[w][lane * 2 + 1] = (char)(m_nxt.y != 0.f);

        // ---- pointer advances (tn clamps -> skip advance at the end) ----
        pO += dF; pZCV += dF;
        if (tt < TT - 2) {
            pXn += dF; pMn += dF; pBn += dF;
            pRRn += dRR; pGQn += dGQ;
        }
        BARSYNC();  // E: h/hr + t+1 row inputs ready
    }
}

// ---------------------------------------------------------------------------
extern "C" void kernel_launch(void* const* d_in, const int* in_sizes, int n_in,
                              void* d_out, int out_size, void* d_ws, size_t ws_size,
                              hipStream_t stream) {
    (void)in_sizes; (void)n_in; (void)out_size; (void)ws_size;
    const float* x        = (const float*)d_in[0];
    const float* m        = (const float*)d_in[1];
    const float* lt       = (const float*)d_in[2];
    const float* fw_Wih   = (const float*)d_in[3];
    const float* fw_Whh   = (const float*)d_in[4];
    const float* fw_bih   = (const float*)d_in[5];
    const float* fw_bhh   = (const float*)d_in[6];
    const float* bw_Wih   = (const float*)d_in[7];
    const float* bw_Whh   = (const float*)d_in[8];
    const float* bw_bih   = (const float*)d_in[9];
    const float* bw_bhh   = (const float*)d_in[10];
    const float* fwlin_W  = (const float*)d_in[11];
    const float* fwlin_b  = (const float*)d_in[12];
    const float* bwlin_W  = (const float*)d_in[13];
    const float* bwlin_b  = (const float*)d_in[14];
    const float* fwz_W    = (const float*)d_in[15];
    const float* fwz_b    = (const float*)d_in[16];
    const float* bwz_W    = (const float*)d_in[17];
    const float* bwz_b    = (const float*)d_in[18];
    const float* fwbeta_W = (const float*)d_in[19];
    const float* fwbeta_b = (const float*)d_in[20];
    const float* bwbeta_W = (const float*)d_in[21];
    const float* bwbeta_b = (const float*)d_in[22];
    const float* lag_W    = (const float*)d_in[23];
    const float* lag_b    = (const float*)d_in[24];
    const float* lagb_W   = (const float*)d_in[25];
    const float* lagb_b   = (const float*)d_in[26];
    const float* rbeta_W  = (const float*)d_in[27];
    const float* rbeta_b  = (const float*)d_in[28];
    const float* rbetab_W = (const float*)d_in[29];
    const float* rbetab_b = (const float*)d_in[30];
    const float* test_W   = (const float*)d_in[31];
    const float* test_b   = (const float*)d_in[32];

    char* ws = (char*)d_ws;
    size_t o = 0;
    auto alloc = [&](size_t bytes) { char* p = ws + o; o += (bytes + 255) & ~(size_t)255; return p; };
    short* lagW0b  = (short*)alloc(65536);
    short* lagW1b  = (short*)alloc(65536);
    short* rbW0b   = (short*)alloc(65536);
    short* rbW1b   = (short*)alloc(65536);
    short* betaW0b = (short*)alloc(196608);
    short* betaW1b = (short*)alloc(196608);
    short* testWb  = (short*)alloc(98304);
    float* s_all   = (float*)alloc(4352 * 4);
    char*  whhQ0   = (char*)alloc(262144);
    char*  whhQ1   = (char*)alloc(262144);
    char*  linQ0   = (char*)alloc(32768);
    char*  linQ1   = (char*)alloc(32768);
    short* wihcB0  = (short*)alloc(262144);
    short* wihcB1  = (short*)alloc(262144);
    short* wihmB0  = (short*)alloc(262144);
    short* wihmB1  = (short*)alloc(262144);
    short* zwB0    = (short*)alloc(32768);
    short* zwB1    = (short*)alloc(32768);
    o = (o + ((size_t)1 << 20) - 1) & ~(((size_t)1 << 20) - 1);
    short* rr0 = (short*)(ws + o); o += (size_t)BTc * 256 * 2;
    short* rr1 = (short*)(ws + o); o += (size_t)BTc * 256 * 2;
    short* rb0 = (short*)(ws + o); o += (size_t)BTc * 128 * 2;
    short* rb1 = (short*)(ws + o); o += (size_t)BTc * 128 * 2;
    short* bt0 = (short*)(ws + o); o += (size_t)BTc * 128 * 2;
    short* bt1 = (short*)(ws + o); o += (size_t)BTc * 128 * 2;
    short* gb0 = (short*)(ws + o); o += (size_t)BTc * 1024 * 2;   // 134 MB
    short* gb1 = (short*)(ws + o); o += (size_t)BTc * 1024 * 2;   // 134 MB

    // ---- launch 1: prep + scales + packb ----
    AArgs aa;
    aa.p.s0 = lag_W;    aa.p.d0 = lagW0b;
    aa.p.s1 = lagb_W;   aa.p.d1 = lagW1b;
    aa.p.s2 = rbeta_W;  aa.p.d2 = rbW0b;
    aa.p.s3 = rbetab_W; aa.p.d3 = rbW1b;
    aa.p.s4 = fwbeta_W; aa.p.d4 = betaW0b;
    aa.p.s5 = bwbeta_W; aa.p.d5 = betaW1b;
    aa.p.s6 = test_W;   aa.p.d6 = testWb;
    aa.s.d[0] = { fw_Whh,  256, 0,   256, 1024, 0 };
    aa.s.d[1] = { bw_Whh,  256, 0,   256, 1024, 1024 };
    aa.s.d[2] = { fw_Wih,  256, 128, 128, 1024, 2048 };
    aa.s.d[3] = { bw_Wih,  256, 128, 128, 1024, 3072 };
    aa.s.d[4] = { fwlin_W, 256, 0,   256, 128,  4096 };
    aa.s.d[5] = { bwlin_W, 256, 0,   256, 128,  4224 };
    aa.s.s = s_all;
    aa.b[0] = { fw_Wih, wihcB0, 256, 0,   4, 0, 16384 };
    aa.b[1] = { bw_Wih, wihcB1, 256, 0,   4, 0, 16384 };
    aa.b[2] = { fwz_W,  zwB0,   128, 0,   4, 1, 2048 };
    aa.b[3] = { bwz_W,  zwB1,   128, 0,   4, 1, 2048 };
    aa.b[4] = { fw_Wih, wihmB0, 256, 128, 4, 0, 16384 };
    aa.b[5] = { bw_Wih, wihmB1, 256, 128, 4, 0, 16384 };
    k_a<<<2832, 256, 0, stream>>>(aa);

    // ---- launch 2: rr_rb + gbase + packq (all independent, overlapped) ----
    BArgs bb;
    bb.lt = lt;
    bb.lagW0 = lagW0b; bb.lagb0 = lag_b;  bb.rbW0 = rbW0b; bb.rbb0 = rbeta_b;
    bb.rr0 = rr0; bb.rb0 = rb0;
    bb.lagW1 = lagW1b; bb.lagb1 = lagb_b; bb.rbW1 = rbW1b; bb.rbb1 = rbetab_b;
    bb.rr1 = rr1; bb.rb1 = rb1;
    bb.m = m; bb.wmB0 = wihmB0; bb.wmB1 = wihmB1; bb.gb0 = gb0; bb.gb1 = gb1;
    bb.q[0] = { fw_Whh,  whhQ0,  256, 0,   8, 0,    32768 };
    bb.q[1] = { bw_Whh,  whhQ1,  256, 0,   8, 1024, 32768 };
    bb.q[2] = { fwlin_W, linQ0,  256, 0,   8, 4096, 4096 };
    bb.q[3] = { bwlin_W, linQ1,  256, 0,   8, 4224, 4096 };
    bb.s = s_all;
    k_b<<<3360, 256, 0, stream>>>(bb);

    // ---- launch 3: beta (both dirs, 32-row blocks) ----
    k_beta2<<<4096, 256, 0, stream>>>(m, rb0, rb1, betaW0b, betaW1b,
                                      fwbeta_b, bwbeta_b, testWb, test_b, bt0, bt1);

    // ---- launch 4: scan ----
    ScanArgs sa;
    sa.x = x; sa.m = m;
    sa.rr0 = rr0; sa.rr1 = rr1; sa.beta0 = bt0; sa.beta1 = bt1;
    sa.gb0 = gb0; sa.gb1 = gb1;
    sa.whh0 = whhQ0; sa.whh1 = whhQ1;
    sa.lin0 = linQ0; sa.lin1 = linQ1;
    sa.wihc0 = wihcB0; sa.wihc1 = wihcB1;
    sa.zw0 = zwB0; sa.zw1 = zwB1;
    sa.s_all = s_all;
    sa.bih0 = fw_bih; sa.bhh0 = fw_bhh; sa.bih1 = bw_bih; sa.bhh1 = bw_bhh;
    sa.linb0 = fwlin_b; sa.linb1 = bwlin_b; sa.zb0 = fwz_b; sa.zb1 = bwz_b;
    sa.out = (float*)d_out;
    k_scan<<<32, 1024, 0, stream>>>(sa);
}

// Round 9
// 4772.618 us; speedup vs baseline: 1.0580x; 1.0580x over previous
//
#include <hip/hip_runtime.h>
#include <stdint.h>

// Problem constants (fixed by reference)
#define TT 256
#define FF 128
#define HH 256
#define BB 256
#define BTc (BB * TT)                    // 65536
#define BTFc ((size_t)BB * TT * FF)      // 8388608 elements per output tensor

typedef __attribute__((ext_vector_type(8))) short short8;
typedef __attribute__((ext_vector_type(4))) float floatx4;
typedef __attribute__((ext_vector_type(4))) int intx4;

__device__ __forceinline__ floatx4 mfma16(short8 a, short8 b, floatx4 c) {
    return __builtin_amdgcn_mfma_f32_16x16x32_bf16(a, b, c, 0, 0, 0);
}
__device__ __forceinline__ intx4 mfmai8(long a, long b, intx4 c) {
    return __builtin_amdgcn_mfma_i32_16x16x32_i8(a, b, c, 0, 0, 0);
}

__device__ __forceinline__ float bf2f(short s) {
    return __uint_as_float(((unsigned)(unsigned short)s) << 16);
}
__device__ __forceinline__ short f2bf(float f) {  // RNE
    unsigned u = __float_as_uint(f);
    u += 0x7FFFu + ((u >> 16) & 1u);
    return (short)(u >> 16);
}
__device__ __forceinline__ short8 ld_cvt8(const float* __restrict__ p) {
    short8 r;
#pragma unroll
    for (int j = 0; j < 8; ++j) r[j] = f2bf(p[j]);
    return r;
}
__device__ __forceinline__ float sigf(float x) { return 1.f / (1.f + __expf(-x)); }
__device__ __forceinline__ float tanhf_(float x) { return 1.f - 2.f / (1.f + __expf(2.f * x)); }

// lgkm-only barrier: LDS handoffs need lgkmcnt(0); global loads/stores get
// their vmcnt waits at USE (compiler-inserted).
#define BARSYNC() do { asm volatile("s_waitcnt lgkmcnt(0)" ::: "memory"); \
                       __builtin_amdgcn_s_barrier(); } while (0)

// ---------------------------------------------------------------------------
// L0: k_p0 — tiny prep: cast the 4 small weights rr_rb needs (512 KB total).
// ---------------------------------------------------------------------------
__global__ __launch_bounds__(256) void k_p0(
    const float* __restrict__ s0, const float* __restrict__ s1,
    const float* __restrict__ s2, const float* __restrict__ s3,
    short* __restrict__ d0, short* __restrict__ d1,
    short* __restrict__ d2, short* __restrict__ d3) {
    int i = blockIdx.x * 256 + threadIdx.x;     // 512 blocks = 131072 elems
    if (i < 32768) { d0[i] = f2bf(s0[i]); return; }  i -= 32768;
    if (i < 32768) { d1[i] = f2bf(s1[i]); return; }  i -= 32768;
    if (i < 32768) { d2[i] = f2bf(s2[i]); return; }
    i -= 32768;
    d3[i] = f2bf(s3[i]);
}

// ---------------------------------------------------------------------------
// L1: k_a = rr_rb (blocks 0..1023, longest pole FIRST) UNION big-prep
// (1024..1983: betaW0/betaW1/testW) UNION scales (1984..3071) UNION packb
// (3072..3343). All branches independent of each other within this launch.
//
// rr_rb (re-blocked, R7 form): block covers 4 batches (one rd group) x 32
// timesteps; rr frag-layout store packs 4 rd-slots into ONE b64.
// ---------------------------------------------------------------------------
struct ScaleDesc { const float* src; int stride; int coloff; int K; int nrows; int sbase; };
struct ScaleArgs { ScaleDesc d[6]; float* s; };
struct PackBDesc { const float* src; short* dst; int stride; int coloff; int kts; int diag; int groups; };
struct AArgs {
    // rr_rb
    const float* lt;
    const short* lagW0; const float* lagb0; const short* rbW0; const float* rbb0;
    short* rr0; short* rb0;
    const short* lagW1; const float* lagb1; const short* rbW1; const float* rbb1;
    short* rr1; short* rb1;
    // big prep
    const float *ps0, *ps1, *ps2; short *pd0, *pd1, *pd2;
    // scales
    ScaleArgs s;
    // packb
    PackBDesc b[6];
};

__global__ __launch_bounds__(256) void k_a(AArgs A) {
    __shared__ short rrS[128][264];          // rr_rb branch only
    const int tid = threadIdx.x, lane = tid & 63, w = tid >> 6;
    const int ln = lane & 15, q4 = lane >> 4;

    if (blockIdx.x < 1024) {
        // ---- rr_rb: rr = exp(-relu(lt @ lagW^T + lagb)) (frag layout),
        //             rb = rr @ rbW^T + rbb ----
        int b = blockIdx.x;
        const int dir = b >> 9; b &= 511;
        const int tc  = b & 7;          // 32-timestep chunk
        const int q4d = (b >> 3) & 3;   // rd group
        const int bg  = b >> 5;         // batch group 0..15
        const short* lagW = dir ? A.lagW1 : A.lagW0;
        const float* lagb = dir ? A.lagb1 : A.lagb0;
        const short* rbW  = dir ? A.rbW1  : A.rbW0;
        const float* rbb  = dir ? A.rbb1  : A.rbb0;
        short* rr = dir ? A.rr1 : A.rr0;
        short* rb = dir ? A.rb1 : A.rb0;
        // tile row r (0..127): batch = bg*16 + q4d*4 + (r>>5), t = tc*32 + (r&31)

#pragma unroll
        for (int mt = 0; mt < 2; ++mt) {
            const int rbase = w * 32 + mt * 16;
            floatx4 acc[16];
#pragma unroll
            for (int nt = 0; nt < 16; ++nt) { floatx4 z = {0.f, 0.f, 0.f, 0.f}; acc[nt] = z; }
            const int r = rbase + ln;
            const size_t aoff = ((size_t)(bg * 16 + q4d * 4 + (r >> 5)) * TT + tc * 32 + (r & 31)) * FF;
#pragma unroll
            for (int kt = 0; kt < 4; ++kt) {
                short8 a = ld_cvt8(A.lt + aoff + kt * 32 + q4 * 8);
#pragma unroll
                for (int nt = 0; nt < 16; ++nt) {
                    short8 bfr = *(const short8*)(lagW + (nt * 16 + ln) * 128 + kt * 32 + q4 * 8);
                    acc[nt] = mfma16(a, bfr, acc[nt]);
                }
            }
#pragma unroll
            for (int nt = 0; nt < 16; ++nt) {
                int n = nt * 16 + ln;
                float bias = lagb[n];
#pragma unroll
                for (int r2 = 0; r2 < 4; ++r2) {
                    int row = rbase + q4 * 4 + r2;
                    rrS[row][n] = f2bf(__expf(-fmaxf(acc[nt][r2] + bias, 0.f)));
                }
            }
        }
        __syncthreads();
        // rr store: pack 4 rd-slots into one b64; coalesced.
        for (int c = tid; c < 32 * 256; c += 256) {
            int tl = c >> 8, n = c & 255;
            unsigned long long pk =
                ((unsigned long long)(unsigned short)rrS[tl][n]) |
                ((unsigned long long)(unsigned short)rrS[32 + tl][n] << 16) |
                ((unsigned long long)(unsigned short)rrS[64 + tl][n] << 32) |
                ((unsigned long long)(unsigned short)rrS[96 + tl][n] << 48);
            size_t doff = ((((size_t)(bg * TT + tc * 32 + tl) * 16 + (n >> 4)) * 64)
                           + q4d * 16 + (n & 15)) * 4;
            *(unsigned long long*)(rr + doff) = pk;
        }
#pragma unroll
        for (int mt = 0; mt < 2; ++mt) {
            const int rbase = w * 32 + mt * 16;
            floatx4 acc[8];
#pragma unroll
            for (int nt = 0; nt < 8; ++nt) { floatx4 z = {0.f, 0.f, 0.f, 0.f}; acc[nt] = z; }
#pragma unroll
            for (int kt = 0; kt < 8; ++kt) {
                short8 a = *(const short8*)&rrS[rbase + ln][kt * 32 + q4 * 8];
#pragma unroll
                for (int nt = 0; nt < 8; ++nt) {
                    short8 bfr = *(const short8*)(rbW + (nt * 16 + ln) * 256 + kt * 32 + q4 * 8);
                    acc[nt] = mfma16(a, bfr, acc[nt]);
                }
            }
#pragma unroll
            for (int nt = 0; nt < 8; ++nt) {
                int n = nt * 16 + ln;
                float bias = rbb[n];
#pragma unroll
                for (int r2 = 0; r2 < 4; ++r2) {
                    int row = rbase + q4 * 4 + r2;
                    size_t roff = ((size_t)(bg * 16 + q4d * 4 + (row >> 5)) * TT
                                   + tc * 32 + (row & 31)) * 128;
                    rb[roff + n] = f2bf(acc[nt][r2] + bias);
                }
            }
        }
        return;
    }

    if (blockIdx.x < 1984) {
        // ---- big prep: betaW0, betaW1, testW (fp32 -> bf16 casts) ----
        int i = (blockIdx.x - 1024) * 256 + tid;
        if (i < 98304) { A.pd0[i] = f2bf(A.ps0[i]); return; }  i -= 98304;
        if (i < 98304) { A.pd1[i] = f2bf(A.ps1[i]); return; }  i -= 98304;
        if (i < 49152) { A.pd2[i] = f2bf(A.ps2[i]); return; }
        return;
    }

    if (blockIdx.x < 3072) {
        // ---- scales: per-row absmax ----
        int gw = ((blockIdx.x - 1984) * 256 + tid) >> 6;
#pragma unroll 1
        for (int i = 0; i < 6; ++i) {
            if (gw < A.s.d[i].nrows) {
                const float* p = A.s.d[i].src + (size_t)gw * A.s.d[i].stride + A.s.d[i].coloff;
                float amax = 0.f;
                for (int j = lane; j < A.s.d[i].K; j += 64) amax = fmaxf(amax, fabsf(p[j]));
#pragma unroll
                for (int off = 32; off; off >>= 1) amax = fmaxf(amax, __shfl_xor(amax, off, 64));
                if (lane == 0) A.s.s[A.s.d[i].sbase + gw] = fmaxf(amax, 1e-20f);
                return;
            }
            gw -= A.s.d[i].nrows;
        }
        return;
    }

    // ---- packb: fp32 [N,K] row-major -> bf16 frag-major ----
    int g = (blockIdx.x - 3072) * 256 + tid;
#pragma unroll 1
    for (int i = 0; i < 6; ++i) {
        const PackBDesc& D = A.b[i];
        if (g < D.groups) {
            int frag = g >> 6, plane = g & 63;
            int nt = frag >> 2, kt = frag & 3;   // kts==4 for all entries
            int pln = plane & 15, pq4 = plane >> 4;
            int row = nt * 16 + pln;
            const float* p = D.src + (size_t)row * D.stride + D.coloff + kt * 32 + pq4 * 8;
            short* dp = D.dst + (size_t)g * 8;
#pragma unroll
            for (int j = 0; j < 8; ++j) {
                int col = kt * 32 + pq4 * 8 + j;
                float v = p[j];
                if (D.diag && col == row) v = 0.f;
                dp[j] = f2bf(v);
            }
            return;
        }
        g -= D.groups;
    }
}

// ---------------------------------------------------------------------------
// L2: k_c = beta2 (blocks 0..4095, 32-row tiles) UNION gbase (4096..6143)
// UNION packq (6144..6431). All independent; beta2 (long pole) first.
// ---------------------------------------------------------------------------
struct PackQDesc { const float* src; char* dst; int stride; int coloff; int kts; int sbase; int groups; };
struct CArgs {
    // beta2
    const float* m;
    const short* rb0; const short* rb1;
    const short* bW0; const short* bW1;
    const float* bb0; const float* bb1;
    const short* tW; const float* tb;
    short* bt0; short* bt1;
    // gbase
    const short* wmB0; const short* wmB1;
    short* gb0; short* gb1;
    // packq
    PackQDesc q[4]; const float* s;
};

__global__ __launch_bounds__(256) void k_c(CArgs A) {
    __shared__ short uS[32][392];            // beta2 branch only
    const int tid = threadIdx.x, lane = tid & 63, w = tid >> 6;
    const int ln = lane & 15, q4 = lane >> 4;

    if (blockIdx.x < 4096) {
        // ---- beta2: u = sigmoid(concat(m,rb) @ bW^T + bb); beta = u@tW^T+tb
        const int dir = blockIdx.x >> 11;
        const size_t r0 = (size_t)(blockIdx.x & 2047) * 32;
        const short* rb = dir ? A.rb1 : A.rb0;
        const short* bW = dir ? A.bW1 : A.bW0;
        const float* bb = dir ? A.bb1 : A.bb0;
        short* bout = dir ? A.bt1 : A.bt0;
        const int rt = w >> 1;        // row-tile 0/1
        const int nh = w & 1;         // n-half

        {
            floatx4 acc[12];
#pragma unroll
            for (int j = 0; j < 12; ++j) { floatx4 z = {0.f, 0.f, 0.f, 0.f}; acc[j] = z; }
#pragma unroll
            for (int kt = 0; kt < 8; ++kt) {
                short8 a;
                if (kt < 4) a = ld_cvt8(A.m + (r0 + rt * 16 + ln) * 128 + kt * 32 + q4 * 8);
                else        a = *(const short8*)(rb + (r0 + rt * 16 + ln) * 128 + (kt - 4) * 32 + q4 * 8);
#pragma unroll
                for (int j = 0; j < 12; ++j) {
                    int nt = nh * 12 + j;
                    short8 b = *(const short8*)(bW + (nt * 16 + ln) * 256 + kt * 32 + q4 * 8);
                    acc[j] = mfma16(a, b, acc[j]);
                }
            }
#pragma unroll
            for (int j = 0; j < 12; ++j) {
                int n = (nh * 12 + j) * 16 + ln;
                float bias = bb[n];
#pragma unroll
                for (int r = 0; r < 4; ++r)
                    uS[rt * 16 + q4 * 4 + r][n] = f2bf(sigf(acc[j][r] + bias));
            }
        }
        __syncthreads();
        {
            floatx4 acc[4];
#pragma unroll
            for (int j = 0; j < 4; ++j) { floatx4 z = {0.f, 0.f, 0.f, 0.f}; acc[j] = z; }
#pragma unroll
            for (int kt = 0; kt < 12; ++kt) {
                short8 a = *(const short8*)&uS[rt * 16 + ln][kt * 32 + q4 * 8];
#pragma unroll
                for (int j = 0; j < 4; ++j) {
                    int nt = nh * 4 + j;
                    short8 b = *(const short8*)(A.tW + (nt * 16 + ln) * 384 + kt * 32 + q4 * 8);
                    acc[j] = mfma16(a, b, acc[j]);
                }
            }
#pragma unroll
            for (int j = 0; j < 4; ++j) {
                int n = (nh * 4 + j) * 16 + ln;
                float bias = A.tb[n];
#pragma unroll
                for (int r = 0; r < 4; ++r)
                    bout[(r0 + rt * 16 + q4 * 4 + r) * 128 + n] = f2bf(acc[j][r] + bias);
            }
        }
        return;
    }

    if (blockIdx.x < 6144) {
        // ---- gbase: gbase[b,t,n] = WihM @ m(b,t)  (bf16, scan frag layout) ----
        int task = (blockIdx.x - 4096) * 4 + w;   // 0..8191
        const int dir = task >> 12; task &= 4095; // bg*256 + t
        const int bg = task >> 8, t = task & 255;
        const short* wB = dir ? A.wmB1 : A.wmB0;
        short* gb = dir ? A.gb1 : A.gb0;

        short8 a[4];
#pragma unroll
        for (int kt = 0; kt < 4; ++kt)
            a[kt] = ld_cvt8(A.m + ((size_t)(bg * 16 + ln) * TT + t) * FF + kt * 32 + q4 * 8);

        short* dst = gb + (size_t)task * 16384 + lane * 4;
#pragma unroll 2
        for (int nt = 0; nt < 64; ++nt) {
            floatx4 acc = {0.f, 0.f, 0.f, 0.f};
#pragma unroll
            for (int kt = 0; kt < 4; ++kt) {
                short8 bfr = *(const short8*)(wB + (nt * 4 + kt) * 512 + lane * 8);
                acc = mfma16(a[kt], bfr, acc);
            }
            unsigned long long pk =
                ((unsigned long long)(unsigned short)f2bf(acc[0])) |
                ((unsigned long long)(unsigned short)f2bf(acc[1]) << 16) |
                ((unsigned long long)(unsigned short)f2bf(acc[2]) << 32) |
                ((unsigned long long)(unsigned short)f2bf(acc[3]) << 48);
            *(unsigned long long*)(dst + nt * 256) = pk;
        }
        return;
    }

    // ---- packq ----
    int g = (blockIdx.x - 6144) * 256 + tid;
#pragma unroll 1
    for (int i = 0; i < 4; ++i) {
        const PackQDesc& D = A.q[i];
        if (g < D.groups) {
            int frag = g >> 6, plane = g & 63;
            int nt = frag / D.kts, kt = frag - nt * D.kts;
            int pln = plane & 15, pq4 = plane >> 4;
            int row = nt * 16 + pln;
            const float* p = D.src + (size_t)row * D.stride + D.coloff + kt * 32 + pq4 * 8;
            float inv = 127.f / A.s[D.sbase + row];
            char* dp = D.dst + (size_t)g * 8;
#pragma unroll
            for (int j = 0; j < 8; ++j) {
                int q = __float2int_rn(p[j] * inv);
                q = q > 127 ? 127 : (q < -127 ? -127 : q);
                dp[j] = (char)q;
            }
            return;
        }
        g -= D.groups;
    }
}

// ---------------------------------------------------------------------------
// k_scan: EXACT R7/v4 (best-measured 3890-3925 us) — role-split 3-barrier
// schedule. FROZEN: R5 (setprio/reg-pipeline) regressed +11%; R8
// (pointerization) was null — the compiler already optimizes addressing; the
// remaining per-step cost is the structural latency floor of this
// decomposition (3 LDS-handoff barriers x dependent MFMA/transcendental
// chains x 256 serial steps at 1 block/CU).
// ---------------------------------------------------------------------------
struct ScanArgs {
    const float* x; const float* m;
    const short* rr0; const short* rr1;      // frag layout (see k_a)
    const short* beta0; const short* beta1;
    const short* gb0; const short* gb1;      // gbase frag layout
    const char* whh0; const char* whh1;
    const char* lin0; const char* lin1;
    const short* wihc0; const short* wihc1;
    const short* zw0; const short* zw1;
    const float* s_all;
    const float* bih0; const float* bhh0; const float* bih1; const float* bhh1;
    const float* linb0; const float* linb1; const float* zb0; const float* zb1;
    float* out;
};

__global__ __launch_bounds__(1024, 4) void k_scan(ScanArgs A) {
    const int tid = threadIdx.x;
    const int lane = tid & 63;
    const int w = tid >> 6;       // 0..15
    const int ln = lane & 15;
    const int q4 = lane >> 4;     // 0..3
    const int dir = blockIdx.x >> 4;
    const int bgi = blockIdx.x & 15;
    const int bg0 = bgi * 16;

    const short* rrF   = dir ? A.rr1   : A.rr0;
    const short* beta  = dir ? A.beta1 : A.beta0;
    const short* gbF   = dir ? A.gb1   : A.gb0;
    const char*  whhQ  = dir ? A.whh1  : A.whh0;
    const char*  linQ  = dir ? A.lin1  : A.lin0;
    const short* wihcB = dir ? A.wihc1 : A.wihc0;
    const short* zwB   = dir ? A.zw1   : A.zw0;
    const float* bih   = dir ? A.bih1  : A.bih0;
    const float* bhh   = dir ? A.bhh1  : A.bhh0;
    const float* linb  = dir ? A.linb1 : A.linb0;
    const float* zb    = dir ? A.zb1   : A.zb0;
    const int so_whh  = dir ? 1024 : 0;
    const int so_lin  = 4096 + (dir ? 128 : 0);

    __shared__ char  hS8[16][264];    // h  in i8 (x127)
    __shared__ char  hrS8[16][264];   // h*r in i8 (x127)
    __shared__ char  msS8[16][136];   // m in i8 {0,1}
    __shared__ short xS[16][136];     // x(t) rows, bf16
    __shared__ short bS[16][136];     // beta(t) rows, bf16
    __shared__ short outS[16][136];   // out bf16
    __shared__ short ccS[16][136];    // c_c bf16
    __shared__ short zwS[16384];      // masked zW, bf16 frag-major (32 KB)
    __shared__ char  linS8[32768];    // lin i8 frag-major (32 KB)

    // ---- pinned Whh i8 fragments: 4 gates x 8 kt x 2 VGPR = 64 regs ----
    long WhhP[4][8];
#pragma unroll
    for (int q = 0; q < 4; ++q)
#pragma unroll
        for (int kt = 0; kt < 8; ++kt)
            WhhP[q][kt] = *(const long*)(whhQ + (((w + 16 * q) * 8 + kt) * 512 + lane * 8));

    float fhh[4], gb[4];
#pragma unroll
    for (int q = 0; q < 4; ++q) {
        int n = (w + 16 * q) * 16 + ln;
        fhh[q] = A.s_all[so_whh + n] * (1.f / 16129.f);   // (s/127)*(1/127)
        gb[q]  = bih[n] + bhh[n];
    }
    float flin = 0.f, lb;
    if (w < 8) { int n = w * 16 + ln; flin = A.s_all[so_lin + n] * (1.f / 16129.f); lb = linb[n]; }
    else       { lb = zb[(w - 8) * 16 + ln]; }

    for (int i = tid; i < 16384; i += 1024) zwS[i] = zwB[i];
    for (int i = tid; i < 4096; i += 1024) ((long*)linS8)[i] = ((const long*)linQ)[i];
    for (int i = tid; i < 16 * 264; i += 1024) { hS8[i / 264][i % 264] = 0; hrS8[i / 264][i % 264] = 0; }

    // gates = Whh*(h*r) [i8 pinned] + gbase [prefetched] + bias
    auto GATES = [&](floatx4 (&g)[4], const long (&gq)[4]) {
#pragma unroll
        for (int pass = 0; pass < 2; ++pass) {
            const int q0 = pass * 2, q1 = pass * 2 + 1;
            intx4 gi0 = {0, 0, 0, 0}, gi1 = {0, 0, 0, 0};
#pragma unroll
            for (int kt = 0; kt < 8; ++kt) {
                long hrf = *(const long*)&hrS8[ln][kt * 32 + q4 * 8];
                gi0 = mfmai8(hrf, WhhP[q0][kt], gi0);
                gi1 = mfmai8(hrf, WhhP[q1][kt], gi1);
            }
#pragma unroll
            for (int r = 0; r < 4; ++r) {
                g[q0][r] = (float)gi0[r] * fhh[q0]
                         + bf2f((short)(((unsigned long long)gq[q0]) >> (16 * r))) + gb[q0];
                g[q1][r] = (float)gi1[r] * fhh[q1]
                         + bf2f((short)(((unsigned long long)gq[q1]) >> (16 * r))) + gb[q1];
            }
        }
    };

    const int tfirst = dir ? (TT - 1) : 0;
    {   // stage step-0 row inputs
        float2 xf = *(const float2*)(A.x + ((size_t)(bg0 + w) * TT + tfirst) * FF + lane * 2);
        float2 mf2 = *(const float2*)(A.m + ((size_t)(bg0 + w) * TT + tfirst) * FF + lane * 2);
        int    bf = *(const int*)(beta + ((size_t)(bg0 + w) * TT + tfirst) * FF + lane * 2);
        xS[w][lane * 2 + 0] = f2bf(xf.x);
        xS[w][lane * 2 + 1] = f2bf(xf.y);
        *(int*)&bS[w][lane * 2] = bf;
        msS8[w][lane * 2 + 0] = (char)(mf2.x != 0.f);
        msS8[w][lane * 2 + 1] = (char)(mf2.y != 0.f);
    }
    long gq[4];
#pragma unroll
    for (int q = 0; q < 4; ++q)
        gq[q] = *(const long*)(gbF + (((size_t)(bgi * TT + tfirst) * 64) + (w + 16 * q)) * 256
                                     + lane * 4);
    floatx4 cfr = {0.f, 0.f, 0.f, 0.f};
    __syncthreads();

    for (int tt = 0; tt < TT; ++tt) {
        const int t = dir ? (TT - 1 - tt) : tt;
        const int tn = dir ? (t > 0 ? t - 1 : 0) : (t < TT - 1 ? t + 1 : t);
        const size_t rowoffn = ((size_t)(bg0 + w) * TT + tn) * FF;

        // ---- P0: next-step row prefetches (staged at P3, full-step slack) ----
        float2 x_nxt = *(const float2*)(A.x + rowoffn + lane * 2);
        float2 m_nxt = *(const float2*)(A.m + rowoffn + lane * 2);
        int    b_nxt = *(const int*)(beta + rowoffn + lane * 2);
        unsigned long long rrv = *(const unsigned long long*)
            (rrF + ((((size_t)(bgi * TT + tn) * 16 + w) * 64) + lane) * 4);

        // ---- P1: role-split. w>=8: gates.  w<8: out = h @ linW^T + b ----
        floatx4 g[4];
        if (w >= 8) {
            GATES(g, gq);
        } else {
            intx4 oi = {0, 0, 0, 0};
#pragma unroll
            for (int kt = 0; kt < 8; ++kt) {
                long lf = *(const long*)&linS8[(w * 8 + kt) * 512 + lane * 8];
                long hf = *(const long*)&hS8[ln][kt * 32 + q4 * 8];
                oi = mfmai8(hf, lf, oi);
            }
#pragma unroll
            for (int r = 0; r < 4; ++r)
                outS[q4 * 4 + r][w * 16 + ln] = f2bf((float)oi[r] * flin + lb);
        }
        BARSYNC();  // A: outS ready

        // ---- P2: w>=8: z-chain.  w<8: own gates + out store ----
        if (w >= 8) {
            floatx4 zv = {lb, lb, lb, lb};
#pragma unroll
            for (int kt = 0; kt < 4; ++kt) {
                const int c8 = kt * 32 + q4 * 8;
                short8 xv = *(const short8*)&xS[ln][c8];
                short8 ov = *(const short8*)&outS[ln][c8];
                unsigned long long mv = *(const unsigned long long*)&msS8[ln][c8];
                short8 xc;
#pragma unroll
                for (int j = 0; j < 8; ++j)
                    xc[j] = ((mv >> (8 * j)) & 0xffULL) ? xv[j] : ov[j];
                short8 zf = *(const short8*)&zwS[((w - 8) * 4 + kt) * 512 + lane * 8];
                zv = mfma16(xc, zf, zv);
            }
#pragma unroll
            for (int r = 0; r < 4; ++r) {
                const int row = q4 * 4 + r, col = (w - 8) * 16 + ln;
                short z16 = f2bf(zv[r]);
                float z0 = bf2f(z16);
                float o  = bf2f(outS[row][col]);
                float b  = bf2f(bS[row][col]);
                float cv = b * z0 + (1.f - b) * o;
                ccS[row][col] = msS8[row][col] ? xS[row][col] : f2bf(cv);
                size_t ob = (size_t)dir * 3 * BTFc + ((size_t)(bg0 + row) * TT + t) * FF + col;
                A.out[ob + BTFc]     = z0;
                A.out[ob + 2 * BTFc] = cv;
            }
        } else {
            {   // out store: wave w covers rows 2w, 2w+1
                const int orow = 2 * w + (lane >> 5);
                const int ocol = (lane & 31) * 4;
                long ov4 = *(const long*)&outS[orow][ocol];
                float4 vo;
                vo.x = bf2f((short)(ov4));
                vo.y = bf2f((short)(ov4 >> 16));
                vo.z = bf2f((short)(ov4 >> 32));
                vo.w = bf2f((short)(ov4 >> 48));
                size_t ob = (size_t)dir * 3 * BTFc + ((size_t)(bg0 + orow) * TT + t) * FF + ocol;
                *(float4*)(A.out + ob) = vo;
            }
            GATES(g, gq);
        }
        BARSYNC();  // D: ccS ready

        // ---- P3: gq prefetch (t+1); gates += WihC * c_c; pointwise; stage ----
#pragma unroll
        for (int q = 0; q < 4; ++q)
            gq[q] = *(const long*)(gbF + (((size_t)(bgi * TT + tn) * 64) + (w + 16 * q)) * 256
                                         + lane * 4);
#pragma unroll
        for (int kt = 0; kt < 4; ++kt) {
            short8 ccf = *(const short8*)&ccS[ln][kt * 32 + q4 * 8];
#pragma unroll
            for (int q = 0; q < 4; ++q) {
                short8 wc = *(const short8*)(wihcB + ((w + 16 * q) * 4 + kt) * 512 + lane * 8);
                g[q] = mfma16(ccf, wc, g[q]);
            }
        }
#pragma unroll
        for (int r = 0; r < 4; ++r) {
            float gi_ = g[0][r], gf_ = g[1][r], gg_ = g[2][r], go_ = g[3][r];
            float c2 = sigf(gf_) * cfr[r] + sigf(gi_) * tanhf_(gg_);
            float h2 = sigf(go_) * tanhf_(c2);
            cfr[r] = c2;
            float rv = bf2f((short)(rrv >> (16 * r)));
            hS8[q4 * 4 + r][w * 16 + ln]  = (char)__float2int_rn(h2 * 127.f);
            hrS8[q4 * 4 + r][w * 16 + ln] = (char)__float2int_rn(h2 * rv * 127.f);
        }
        xS[w][lane * 2 + 0] = f2bf(x_nxt.x);
        xS[w][lane * 2 + 1] = f2bf(x_nxt.y);
        *(int*)&bS[w][lane * 2] = b_nxt;
        msS8[w][lane * 2 + 0] = (char)(m_nxt.x != 0.f);
        msS8[w][lane * 2 + 1] = (char)(m_nxt.y != 0.f);
        BARSYNC();  // E: h/hr + t+1 row inputs ready
    }
}

// ---------------------------------------------------------------------------
extern "C" void kernel_launch(void* const* d_in, const int* in_sizes, int n_in,
                              void* d_out, int out_size, void* d_ws, size_t ws_size,
                              hipStream_t stream) {
    (void)in_sizes; (void)n_in; (void)out_size; (void)ws_size;
    const float* x        = (const float*)d_in[0];
    const float* m        = (const float*)d_in[1];
    const float* lt       = (const float*)d_in[2];
    const float* fw_Wih   = (const float*)d_in[3];
    const float* fw_Whh   = (const float*)d_in[4];
    const float* fw_bih   = (const float*)d_in[5];
    const float* fw_bhh   = (const float*)d_in[6];
    const float* bw_Wih   = (const float*)d_in[7];
    const float* bw_Whh   = (const float*)d_in[8];
    const float* bw_bih   = (const float*)d_in[9];
    const float* bw_bhh   = (const float*)d_in[10];
    const float* fwlin_W  = (const float*)d_in[11];
    const float* fwlin_b  = (const float*)d_in[12];
    const float* bwlin_W  = (const float*)d_in[13];
    const float* bwlin_b  = (const float*)d_in[14];
    const float* fwz_W    = (const float*)d_in[15];
    const float* fwz_b    = (const float*)d_in[16];
    const float* bwz_W    = (const float*)d_in[17];
    const float* bwz_b    = (const float*)d_in[18];
    const float* fwbeta_W = (const float*)d_in[19];
    const float* fwbeta_b = (const float*)d_in[20];
    const float* bwbeta_W = (const float*)d_in[21];
    const float* bwbeta_b = (const float*)d_in[22];
    const float* lag_W    = (const float*)d_in[23];
    const float* lag_b    = (const float*)d_in[24];
    const float* lagb_W   = (const float*)d_in[25];
    const float* lagb_b   = (const float*)d_in[26];
    const float* rbeta_W  = (const float*)d_in[27];
    const float* rbeta_b  = (const float*)d_in[28];
    const float* rbetab_W = (const float*)d_in[29];
    const float* rbetab_b = (const float*)d_in[30];
    const float* test_W   = (const float*)d_in[31];
    const float* test_b   = (const float*)d_in[32];

    char* ws = (char*)d_ws;
    size_t o = 0;
    auto alloc = [&](size_t bytes) { char* p = ws + o; o += (bytes + 255) & ~(size_t)255; return p; };
    short* lagW0b  = (short*)alloc(65536);
    short* lagW1b  = (short*)alloc(65536);
    short* rbW0b   = (short*)alloc(65536);
    short* rbW1b   = (short*)alloc(65536);
    short* betaW0b = (short*)alloc(196608);
    short* betaW1b = (short*)alloc(196608);
    short* testWb  = (short*)alloc(98304);
    float* s_all   = (float*)alloc(4352 * 4);
    char*  whhQ0   = (char*)alloc(262144);
    char*  whhQ1   = (char*)alloc(262144);
    char*  linQ0   = (char*)alloc(32768);
    char*  linQ1   = (char*)alloc(32768);
    short* wihcB0  = (short*)alloc(262144);
    short* wihcB1  = (short*)alloc(262144);
    short* wihmB0  = (short*)alloc(262144);
    short* wihmB1  = (short*)alloc(262144);
    short* zwB0    = (short*)alloc(32768);
    short* zwB1    = (short*)alloc(32768);
    o = (o + ((size_t)1 << 20) - 1) & ~(((size_t)1 << 20) - 1);
    short* rr0 = (short*)(ws + o); o += (size_t)BTc * 256 * 2;
    short* rr1 = (short*)(ws + o); o += (size_t)BTc * 256 * 2;
    short* rb0 = (short*)(ws + o); o += (size_t)BTc * 128 * 2;
    short* rb1 = (short*)(ws + o); o += (size_t)BTc * 128 * 2;
    short* bt0 = (short*)(ws + o); o += (size_t)BTc * 128 * 2;
    short* bt1 = (short*)(ws + o); o += (size_t)BTc * 128 * 2;
    short* gb0 = (short*)(ws + o); o += (size_t)BTc * 1024 * 2;   // 134 MB
    short* gb1 = (short*)(ws + o); o += (size_t)BTc * 1024 * 2;   // 134 MB

    // ---- L0: tiny prep (lagW x2, rbW x2 -> bf16; feeds L1's rr_rb) ----
    k_p0<<<512, 256, 0, stream>>>(lag_W, lagb_W, rbeta_W, rbetab_W,
                                  lagW0b, lagW1b, rbW0b, rbW1b);

    // ---- L1: rr_rb (first) + big-prep + scales + packb ----
    AArgs aa;
    aa.lt = lt;
    aa.lagW0 = lagW0b; aa.lagb0 = lag_b;  aa.rbW0 = rbW0b; aa.rbb0 = rbeta_b;
    aa.rr0 = rr0; aa.rb0 = rb0;
    aa.lagW1 = lagW1b; aa.lagb1 = lagb_b; aa.rbW1 = rbW1b; aa.rbb1 = rbetab_b;
    aa.rr1 = rr1; aa.rb1 = rb1;
    aa.ps0 = fwbeta_W; aa.pd0 = betaW0b;
    aa.ps1 = bwbeta_W; aa.pd1 = betaW1b;
    aa.ps2 = test_W;   aa.pd2 = testWb;
    aa.s.d[0] = { fw_Whh,  256, 0,   256, 1024, 0 };
    aa.s.d[1] = { bw_Whh,  256, 0,   256, 1024, 1024 };
    aa.s.d[2] = { fw_Wih,  256, 128, 128, 1024, 2048 };
    aa.s.d[3] = { bw_Wih,  256, 128, 128, 1024, 3072 };
    aa.s.d[4] = { fwlin_W, 256, 0,   256, 128,  4096 };
    aa.s.d[5] = { bwlin_W, 256, 0,   256, 128,  4224 };
    aa.s.s = s_all;
    aa.b[0] = { fw_Wih, wihcB0, 256, 0,   4, 0, 16384 };
    aa.b[1] = { bw_Wih, wihcB1, 256, 0,   4, 0, 16384 };
    aa.b[2] = { fwz_W,  zwB0,   128, 0,   4, 1, 2048 };
    aa.b[3] = { bwz_W,  zwB1,   128, 0,   4, 1, 2048 };
    aa.b[4] = { fw_Wih, wihmB0, 256, 128, 4, 0, 16384 };
    aa.b[5] = { bw_Wih, wihmB1, 256, 128, 4, 0, 16384 };
    k_a<<<3344, 256, 0, stream>>>(aa);

    // ---- L2: beta2 (first) + gbase + packq ----
    CArgs cc;
    cc.m = m;
    cc.rb0 = rb0; cc.rb1 = rb1;
    cc.bW0 = betaW0b; cc.bW1 = betaW1b;
    cc.bb0 = fwbeta_b; cc.bb1 = bwbeta_b;
    cc.tW = testWb; cc.tb = test_b;
    cc.bt0 = bt0; cc.bt1 = bt1;
    cc.wmB0 = wihmB0; cc.wmB1 = wihmB1;
    cc.gb0 = gb0; cc.gb1 = gb1;
    cc.q[0] = { fw_Whh,  whhQ0,  256, 0,   8, 0,    32768 };
    cc.q[1] = { bw_Whh,  whhQ1,  256, 0,   8, 1024, 32768 };
    cc.q[2] = { fwlin_W, linQ0,  256, 0,   8, 4096, 4096 };
    cc.q[3] = { bwlin_W, linQ1,  256, 0,   8, 4224, 4096 };
    cc.s = s_all;
    k_c<<<6432, 256, 0, stream>>>(cc);

    // ---- L3: scan ----
    ScanArgs sa;
    sa.x = x; sa.m = m;
    sa.rr0 = rr0; sa.rr1 = rr1; sa.beta0 = bt0; sa.beta1 = bt1;
    sa.gb0 = gb0; sa.gb1 = gb1;
    sa.whh0 = whhQ0; sa.whh1 = whhQ1;
    sa.lin0 = linQ0; sa.lin1 = linQ1;
    sa.wihc0 = wihcB0; sa.wihc1 = wihcB1;
    sa.zw0 = zwB0; sa.zw1 = zwB1;
    sa.s_all = s_all;
    sa.bih0 = fw_bih; sa.bhh0 = fw_bhh; sa.bih1 = bw_bih; sa.bhh1 = bw_bhh;
    sa.linb0 = fwlin_b; sa.linb1 = bwlin_b; sa.zb0 = fwz_b; sa.zb1 = bwz_b;
    sa.out = (float*)d_out;
    k_scan<<<32, 1024, 0, stream>>>(sa);
}